// Round 2
// baseline (936.296 us; speedup 1.0000x reference)
//
#include <hip/hip_runtime.h>
#include <hip/hip_bf16.h>

#define NNODE 50000
#define DIM   256
#define EDGES 400000
#define NET   4
#define NTOT  (NET * NNODE)     // 200000
#define BSH   7
#define NBUCK ((NTOT + 127) >> BSH)   // 1563

typedef __attribute__((ext_vector_type(8))) __bf16 bf16x8;
typedef __attribute__((ext_vector_type(4))) float f32x4;
typedef __attribute__((ext_vector_type(4))) unsigned short u16x4;
typedef __attribute__((ext_vector_type(8))) unsigned short u16x8;

__device__ __forceinline__ float bf2f(unsigned short u) {
  unsigned int x = ((unsigned int)u) << 16;
  return __builtin_bit_cast(float, x);
}
__device__ __forceinline__ unsigned short f2bf(float f) {
  __hip_bfloat16 h = __float2bfloat16(f);   // RTNE
  return __builtin_bit_cast(unsigned short, h);
}

__global__ void conv_f32_bf16(const float* __restrict__ in, unsigned short* __restrict__ out, int n4) {
  int i = blockIdx.x * blockDim.x + threadIdx.x;
  if (i >= n4) return;
  f32x4 v = reinterpret_cast<const f32x4*>(in)[i];
  u16x4 o;
  o[0] = f2bf(v[0]); o[1] = f2bf(v[1]); o[2] = f2bf(v[2]); o[3] = f2bf(v[3]);
  reinterpret_cast<u16x4*>(out)[i] = o;
}

// Transpose+convert 6 weight matrices: T[n*256+k] = bf16(W[k*256+n])
__global__ void conv_wT(const float* __restrict__ w0, const float* __restrict__ w1,
                        const float* __restrict__ w2, const float* __restrict__ w3,
                        const float* __restrict__ w4, const float* __restrict__ w5,
                        unsigned short* __restrict__ t0, unsigned short* __restrict__ t1,
                        unsigned short* __restrict__ t2, unsigned short* __restrict__ t3,
                        unsigned short* __restrict__ t4, unsigned short* __restrict__ t5) {
  int m = blockIdx.y;
  const float* W = (m == 0) ? w0 : (m == 1) ? w1 : (m == 2) ? w2 : (m == 3) ? w3 : (m == 4) ? w4 : w5;
  unsigned short* T = (m == 0) ? t0 : (m == 1) ? t1 : (m == 2) ? t2 : (m == 3) ? t3 : (m == 4) ? t4 : t5;
  int n = blockIdx.x;           // output row (= W column)
  int k = threadIdx.x;          // 256 threads
  T[n * 256 + k] = f2bf(W[k * 256 + n]);
}

__global__ void zero_i32(int* __restrict__ p, int n) {
  int i = blockIdx.x * blockDim.x + threadIdx.x;
  if (i < n) p[i] = 0;
}

__global__ void fill_f32(float* __restrict__ p, float v, int n) {
  int i = blockIdx.x * blockDim.x + threadIdx.x;
  if (i < n) p[i] = v;
}

// ---- bucketed CSR build ----
#define EPB 6400   // edges per hist block; grid.x = ceil(EDGES/EPB) = 63

__global__ void bucket_hist(const int* __restrict__ d0, const int* __restrict__ d1,
                            const int* __restrict__ d2, const int* __restrict__ d3,
                            int* __restrict__ bcnt) {
  __shared__ int h[NBUCK];
  for (int i = threadIdx.x; i < NBUCK; i += 256) h[i] = 0;
  __syncthreads();
  int t = blockIdx.y;
  const int* dp = (t == 0) ? d0 : (t == 1) ? d1 : (t == 2) ? d2 : d3;
  int base = blockIdx.x * EPB;
  int lim = base + EPB; if (lim > EDGES) lim = EDGES;
  for (int i = base + threadIdx.x; i < lim; i += 256)
    atomicAdd(&h[(t * NNODE + dp[i]) >> BSH], 1);
  __syncthreads();
  for (int i = threadIdx.x; i < NBUCK; i += 256) {
    int v = h[i];
    if (v) atomicAdd(&bcnt[i], v);
  }
}

__global__ void bucket_scan(const int* __restrict__ bcnt, int* __restrict__ bbase,
                            int* __restrict__ bpos, int* __restrict__ S) {
  __shared__ int sh[256];
  int tid = threadIdx.x;
  int vals[7];
  int s = 0;
  #pragma unroll
  for (int j = 0; j < 7; j++) {
    int idx = tid * 7 + j;
    vals[j] = (idx < NBUCK) ? bcnt[idx] : 0;
    s += vals[j];
  }
  sh[tid] = s;
  __syncthreads();
  for (int o = 1; o < 256; o <<= 1) {
    int a = (tid >= o) ? sh[tid - o] : 0;
    __syncthreads();
    sh[tid] += a;
    __syncthreads();
  }
  int run = sh[tid] - s;   // exclusive prefix
  #pragma unroll
  for (int j = 0; j < 7; j++) {
    int idx = tid * 7 + j;
    if (idx < NBUCK) { bbase[idx] = run; bpos[idx] = run; run += vals[j]; }
  }
  if (tid == 255) { bbase[NBUCK] = run; S[NTOT] = run; }  // grand total
}

__global__ void bucket_scatter(const int* __restrict__ s0, const int* __restrict__ s1,
                               const int* __restrict__ s2, const int* __restrict__ s3,
                               const int* __restrict__ d0, const int* __restrict__ d1,
                               const int* __restrict__ d2, const int* __restrict__ d3,
                               int* __restrict__ bpos, unsigned int* __restrict__ pairs) {
  int t = blockIdx.y;
  const int* sp = (t == 0) ? s0 : (t == 1) ? s1 : (t == 2) ? s2 : s3;
  const int* dp = (t == 0) ? d0 : (t == 1) ? d1 : (t == 2) ? d2 : d3;
  int i = blockIdx.x * blockDim.x + threadIdx.x;
  if (i < EDGES) {
    int key = t * NNODE + dp[i];
    int slot = atomicAdd(&bpos[key >> BSH], 1);
    pairs[slot] = ((unsigned int)(key & 127) << 16) | (unsigned int)sp[i];
  }
}

__global__ void bucket_final(const int* __restrict__ bbase, const unsigned int* __restrict__ pairs,
                             int* __restrict__ S, int* __restrict__ srcs) {
  __shared__ int lcnt[128];
  __shared__ int loff[128];
  int b = blockIdx.x;
  int tid = threadIdx.x;
  int beg = bbase[b], end = bbase[b + 1];
  if (tid < 128) lcnt[tid] = 0;
  __syncthreads();
  for (int e = beg + tid; e < end; e += 256)
    atomicAdd(&lcnt[pairs[e] >> 16], 1);
  __syncthreads();
  int c = (tid < 128) ? lcnt[tid] : 0;
  if (tid < 128) loff[tid] = c;
  __syncthreads();
  for (int o = 1; o < 128; o <<= 1) {
    int a = (tid < 128 && tid >= o) ? loff[tid - o] : 0;
    __syncthreads();
    if (tid < 128) loff[tid] += a;
    __syncthreads();
  }
  if (tid < 128) {
    int ex = loff[tid] - c;           // exclusive prefix within bucket
    int key = (b << BSH) + tid;
    if (key < NTOT) S[key] = beg + ex;
    lcnt[tid] = ex;                   // reuse as running cursor
  }
  __syncthreads();
  for (int e = beg + tid; e < end; e += 256) {
    unsigned int p = pairs[e];
    int lk = p >> 16;
    int slot = beg + atomicAdd(&lcnt[lk], 1);
    srcs[slot] = (int)(p & 0xFFFFu);
  }
}

// ---- GEMM: C = X(bf16)[M,256] @ W[256,256] + bias, W given pre-transposed bf16 (WT[n][k]).
// 64x64 tile, 4 waves x 32x32 quadrant, 16x16x32 MFMA. No LDS: WT is L2-resident.
__global__ __launch_bounds__(256) void gemm_bf16(
    const unsigned short* __restrict__ X, const unsigned short* __restrict__ WT,
    const float* __restrict__ bias, unsigned short* __restrict__ out, int M)
{
  int tid = threadIdx.x;
  int m0 = blockIdx.x * 64;
  int n0 = blockIdx.y * 64;
  int wave = tid >> 6, lane = tid & 63;
  int wr = wave >> 1, wc = wave & 1;
  int lrow = lane & 15, kgrp = lane >> 4;
  int rowbase = m0 + 32 * wr;

  f32x4 acc[2][2];
  #pragma unroll
  for (int a = 0; a < 2; a++)
    #pragma unroll
    for (int bq = 0; bq < 2; bq++) acc[a][bq] = (f32x4){0.f, 0.f, 0.f, 0.f};

  int r0 = rowbase + lrow;      if (r0 >= M) r0 = M - 1;
  int r1 = rowbase + 16 + lrow; if (r1 >= M) r1 = M - 1;
  const unsigned short* xp0 = X + (size_t)r0 * 256 + kgrp * 8;
  const unsigned short* xp1 = X + (size_t)r1 * 256 + kgrp * 8;
  const unsigned short* wp0 = WT + (size_t)(n0 + 32 * wc + lrow) * 256 + kgrp * 8;
  const unsigned short* wp1 = WT + (size_t)(n0 + 32 * wc + 16 + lrow) * 256 + kgrp * 8;

  #pragma unroll
  for (int kk = 0; kk < 256; kk += 32) {
    bf16x8 a0 = *reinterpret_cast<const bf16x8*>(xp0 + kk);
    bf16x8 a1 = *reinterpret_cast<const bf16x8*>(xp1 + kk);
    bf16x8 b0 = *reinterpret_cast<const bf16x8*>(wp0 + kk);
    bf16x8 b1 = *reinterpret_cast<const bf16x8*>(wp1 + kk);
    acc[0][0] = __builtin_amdgcn_mfma_f32_16x16x32_bf16(a0, b0, acc[0][0], 0, 0, 0);
    acc[0][1] = __builtin_amdgcn_mfma_f32_16x16x32_bf16(a0, b1, acc[0][1], 0, 0, 0);
    acc[1][0] = __builtin_amdgcn_mfma_f32_16x16x32_bf16(a1, b0, acc[1][0], 0, 0, 0);
    acc[1][1] = __builtin_amdgcn_mfma_f32_16x16x32_bf16(a1, b1, acc[1][1], 0, 0, 0);
  }

  // C/D layout: col = lane&15, row = (lane>>4)*4 + reg  [verified m89/m91]
  #pragma unroll
  for (int mb = 0; mb < 2; mb++) {
    #pragma unroll
    for (int nb = 0; nb < 2; nb++) {
      int col = n0 + 32 * wc + 16 * nb + lrow;
      float bv = bias[col];
      #pragma unroll
      for (int r = 0; r < 4; r++) {
        int row = rowbase + 16 * mb + kgrp * 4 + r;
        if (row < M) out[(size_t)row * 256 + col] = f2bf(acc[mb][nb][r] + bv);
      }
    }
  }
}

// One wave per dst node; fuse the two etypes feeding this ntype:
// mean per etype, sum, optional leaky_relu. MODE 0: bf16 out + relu. MODE 1: f32 out.
template<int MODE>
__global__ void agg2(const int* __restrict__ S, const int* __restrict__ srcs,
                     const unsigned short* __restrict__ whA, int etA,
                     const unsigned short* __restrict__ whB, int etB,
                     void* __restrict__ outp)
{
  int d = blockIdx.x;
  int lane = threadIdx.x;  // 64 lanes x 4 cols
  f32x4 accA = {0.f, 0.f, 0.f, 0.f}, accB = {0.f, 0.f, 0.f, 0.f};

  int gA = etA * NNODE + d;
  int a0 = S[gA], a1 = S[gA + 1];
  for (int e = a0; e < a1; e++) {
    int s = srcs[e];
    u16x4 v = *reinterpret_cast<const u16x4*>(whA + (size_t)s * DIM + lane * 4);
    accA[0] += bf2f(v[0]); accA[1] += bf2f(v[1]); accA[2] += bf2f(v[2]); accA[3] += bf2f(v[3]);
  }
  int gB = etB * NNODE + d;
  int b0 = S[gB], b1 = S[gB + 1];
  for (int e = b0; e < b1; e++) {
    int s = srcs[e];
    u16x4 v = *reinterpret_cast<const u16x4*>(whB + (size_t)s * DIM + lane * 4);
    accB[0] += bf2f(v[0]); accB[1] += bf2f(v[1]); accB[2] += bf2f(v[2]); accB[3] += bf2f(v[3]);
  }
  float ca = (float)(a1 - a0); if (ca < 1.f) ca = 1.f;
  float cb = (float)(b1 - b0); if (cb < 1.f) cb = 1.f;
  float ia = 1.f / ca, ib = 1.f / cb;
  f32x4 r;
  #pragma unroll
  for (int c = 0; c < 4; c++) r[c] = accA[c] * ia + accB[c] * ib;

  if (MODE == 0) {
    u16x4 o;
    #pragma unroll
    for (int c = 0; c < 4; c++) {
      float v = r[c];
      v = (v > 0.f) ? v : 0.01f * v;
      o[c] = f2bf(v);
    }
    reinterpret_cast<u16x4*>((unsigned short*)outp + (size_t)d * DIM)[lane] = o;
  } else {
    reinterpret_cast<f32x4*>((float*)outp + (size_t)d * DIM)[lane] = r;
  }
}

extern "C" void kernel_launch(void* const* d_in, const int* in_sizes, int n_in,
                              void* d_out, int out_size, void* d_ws, size_t ws_size,
                              hipStream_t stream) {
  (void)in_sizes; (void)n_in;
  const float* chem = (const float*)d_in[0];
  const float* gene = (const float*)d_in[1];
  const float *W1[4], *B1[4], *W2[4], *B2[4];
  const int *SRC[4], *DST[4];
  // etype order: 0=ch2ge, 1=ge2ch, 2=ch2ch, 3=ge2ge
  for (int t = 0; t < 4; t++) {
    W1[t]  = (const float*)d_in[2 + 6 * t];
    B1[t]  = (const float*)d_in[3 + 6 * t];
    W2[t]  = (const float*)d_in[4 + 6 * t];
    B2[t]  = (const float*)d_in[5 + 6 * t];
    SRC[t] = (const int*)d_in[6 + 6 * t];
    DST[t] = (const int*)d_in[7 + 6 * t];
  }

  size_t off = 0;
  auto carve = [&](size_t bytes) -> void* {
    void* p = (char*)d_ws + off;
    off += (bytes + 255) & ~(size_t)255;
    return p;
  };
  const size_t FEAT_B = (size_t)NNODE * DIM * 2;  // 25.6 MB bf16
  unsigned short* xb_chem = (unsigned short*)carve(FEAT_B);
  unsigned short* xb_gene = (unsigned short*)carve(FEAT_B);
  unsigned short* wh_a    = (unsigned short*)carve(FEAT_B);  // pairs aliased here (dead before GEMMs)
  unsigned short* wh_b    = (unsigned short*)carve(FEAT_B);
  unsigned short* h1_chem = (unsigned short*)carve(FEAT_B);
  unsigned short* h1_gene = (unsigned short*)carve(FEAT_B);
  int* S    = (int*)carve(((size_t)NTOT + 1) * 4);
  int* srcs = (int*)carve((size_t)NET * EDGES * 4);
  int* bcnt  = (int*)carve((size_t)NBUCK * 4);
  int* bbase = (int*)carve(((size_t)NBUCK + 1) * 4);
  int* bpos  = (int*)carve((size_t)NBUCK * 4);
  // 6 pre-transposed bf16 weight matrices, 128KB each
  unsigned short* WTm[6];
  for (int i = 0; i < 6; i++) WTm[i] = (unsigned short*)carve((size_t)256 * 256 * 2);
  unsigned int* pairs = (unsigned int*)wh_a;  // 6.4MB <= 25.6MB, dead before first GEMM

  if (off > ws_size) {
    fill_f32<<<(out_size + 255) / 256, 256, 0, stream>>>((float*)d_out, (float)(ws_size >> 20), out_size);
    return;
  }

  int n4 = NNODE * DIM / 4;
  conv_f32_bf16<<<(n4 + 255) / 256, 256, 0, stream>>>(chem, xb_chem, n4);
  conv_f32_bf16<<<(n4 + 255) / 256, 256, 0, stream>>>(gene, xb_gene, n4);
  // WTm order: 0=W1[0], 1=W1[1], 2=W1[2], 3=W1[3], 4=W2[1], 5=W2[2]
  conv_wT<<<dim3(256, 6), 256, 0, stream>>>(W1[0], W1[1], W1[2], W1[3], W2[1], W2[2],
                                            WTm[0], WTm[1], WTm[2], WTm[3], WTm[4], WTm[5]);

  // ---- bucketed CSR build ----
  zero_i32<<<(NBUCK + 255) / 256, 256, 0, stream>>>(bcnt, NBUCK);
  bucket_hist<<<dim3((EDGES + EPB - 1) / EPB, 4), 256, 0, stream>>>(DST[0], DST[1], DST[2], DST[3], bcnt);
  bucket_scan<<<1, 256, 0, stream>>>(bcnt, bbase, bpos, S);
  bucket_scatter<<<dim3((EDGES + 255) / 256, 4), 256, 0, stream>>>(
      SRC[0], SRC[1], SRC[2], SRC[3], DST[0], DST[1], DST[2], DST[3], bpos, pairs);
  bucket_final<<<NBUCK, 256, 0, stream>>>(bbase, pairs, S, srcs);

  dim3 ggrid((NNODE + 63) / 64, 4);
  // ---- layer 1, dt = chemical: et1 (ge2ch, src gene) + et2 (ch2ch, src chem)
  gemm_bf16<<<ggrid, 256, 0, stream>>>(xb_gene, WTm[1], B1[1], wh_a, NNODE);
  gemm_bf16<<<ggrid, 256, 0, stream>>>(xb_chem, WTm[2], B1[2], wh_b, NNODE);
  agg2<0><<<NNODE, 64, 0, stream>>>(S, srcs, wh_a, 1, wh_b, 2, h1_chem);
  // ---- layer 1, dt = gene: et0 (ch2ge, src chem) + et3 (ge2ge, src gene)
  gemm_bf16<<<ggrid, 256, 0, stream>>>(xb_chem, WTm[0], B1[0], wh_a, NNODE);
  gemm_bf16<<<ggrid, 256, 0, stream>>>(xb_gene, WTm[3], B1[3], wh_b, NNODE);
  agg2<0><<<NNODE, 64, 0, stream>>>(S, srcs, wh_a, 0, wh_b, 3, h1_gene);
  // ---- layer 2, only dt = chemical needed
  gemm_bf16<<<ggrid, 256, 0, stream>>>(h1_gene, WTm[4], B2[1], wh_a, NNODE);
  gemm_bf16<<<ggrid, 256, 0, stream>>>(h1_chem, WTm[5], B2[2], wh_b, NNODE);
  agg2<1><<<NNODE, 64, 0, stream>>>(S, srcs, wh_a, 1, wh_b, 2, (void*)d_out);
}

// Round 3
// 627.120 us; speedup vs baseline: 1.4930x; 1.4930x over previous
//
#include <hip/hip_runtime.h>
#include <hip/hip_bf16.h>

#define NNODE 50000
#define DIM   256
#define EDGES 400000
#define NET   4
#define NTOT  (NET * NNODE)          // 200000
#define BSH   7
#define NBUCK ((NTOT + 127) >> BSH)  // 1563
#define EPB2  8192                   // edges per chunk
#define CPE   49                     // chunks per etype (49*8192 >= 400000)
#define NBLKT (CPE * NET)            // 196 chunk-blocks total
#define NSCAN (NBUCK * NBLKT)        // 306348

typedef __attribute__((ext_vector_type(8))) __bf16 bf16x8;
typedef __attribute__((ext_vector_type(4))) float f32x4;
typedef __attribute__((ext_vector_type(4))) unsigned short u16x4;
typedef __attribute__((ext_vector_type(8))) unsigned short u16x8;

__device__ __forceinline__ float bf2f(unsigned short u) {
  unsigned int x = ((unsigned int)u) << 16;
  return __builtin_bit_cast(float, x);
}
__device__ __forceinline__ unsigned short f2bf(float f) {
  __hip_bfloat16 h = __float2bfloat16(f);   // RTNE
  return __builtin_bit_cast(unsigned short, h);
}

__global__ void conv_f32_bf16(const float* __restrict__ in, unsigned short* __restrict__ out, int n4) {
  int i = blockIdx.x * blockDim.x + threadIdx.x;
  if (i >= n4) return;
  f32x4 v = reinterpret_cast<const f32x4*>(in)[i];
  u16x4 o;
  o[0] = f2bf(v[0]); o[1] = f2bf(v[1]); o[2] = f2bf(v[2]); o[3] = f2bf(v[3]);
  reinterpret_cast<u16x4*>(out)[i] = o;
}

// Build 3 stacked-K transposed weight matrices: T[n][k] with k<256 from A, k>=256 from B.
__global__ void conv_wT3(const float* __restrict__ a0, const float* __restrict__ b0,
                         const float* __restrict__ a1, const float* __restrict__ b1,
                         const float* __restrict__ a2, const float* __restrict__ b2,
                         unsigned short* __restrict__ t0, unsigned short* __restrict__ t1,
                         unsigned short* __restrict__ t2) {
  int m = blockIdx.y;
  const float* A = (m == 0) ? a0 : (m == 1) ? a1 : a2;
  const float* B = (m == 0) ? b0 : (m == 1) ? b1 : b2;
  unsigned short* T = (m == 0) ? t0 : (m == 1) ? t1 : t2;
  int n = blockIdx.x, k = threadIdx.x;   // 256 threads
  T[n * 512 + k]       = f2bf(A[k * 256 + n]);
  T[n * 512 + 256 + k] = f2bf(B[k * 256 + n]);
}

__global__ void fill_f32(float* __restrict__ p, float v, int n) {
  int i = blockIdx.x * blockDim.x + threadIdx.x;
  if (i < n) p[i] = v;
}

// ---- multi-split CSR build: no per-edge global atomics ----
// K1: per-chunk LDS histogram -> cnt[bucket * NBLKT + chunk]
__global__ void hist_ms(const int* __restrict__ d0, const int* __restrict__ d1,
                        const int* __restrict__ d2, const int* __restrict__ d3,
                        int* __restrict__ cnt) {
  __shared__ int h[NBUCK];
  for (int i = threadIdx.x; i < NBUCK; i += 256) h[i] = 0;
  __syncthreads();
  int t = blockIdx.y, cx = blockIdx.x;
  const int* dp = (t == 0) ? d0 : (t == 1) ? d1 : (t == 2) ? d2 : d3;
  int base = cx * EPB2;
  int lim = base + EPB2; if (lim > EDGES) lim = EDGES;
  for (int i = base + threadIdx.x; i < lim; i += 256)
    atomicAdd(&h[(t * NNODE + dp[i]) >> BSH], 1);
  __syncthreads();
  int blk = t * CPE + cx;
  for (int i = threadIdx.x; i < NBUCK; i += 256)
    cnt[i * NBLKT + blk] = h[i];
}

// hierarchical exclusive scan over NSCAN ints (in place), 4096/block
__global__ void scan_p1(const int* __restrict__ data, int* __restrict__ bsum, int n) {
  __shared__ int red[256];
  int base = blockIdx.x * 4096;
  int s = 0;
  #pragma unroll
  for (int j = 0; j < 16; j++) {
    int idx = base + j * 256 + threadIdx.x;
    s += (idx < n) ? data[idx] : 0;
  }
  red[threadIdx.x] = s;
  __syncthreads();
  for (int o = 128; o > 0; o >>= 1) {
    if (threadIdx.x < o) red[threadIdx.x] += red[threadIdx.x + o];
    __syncthreads();
  }
  if (threadIdx.x == 0) bsum[blockIdx.x] = red[0];
}

__global__ void scan_p2(int* __restrict__ bsum, int nb, int* __restrict__ off, int nscan,
                        int* __restrict__ S) {
  __shared__ int sh[128];
  int tid = threadIdx.x;
  int v = (tid < nb) ? bsum[tid] : 0;
  sh[tid] = v;
  __syncthreads();
  for (int o = 1; o < 128; o <<= 1) {
    int a = (tid >= o) ? sh[tid - o] : 0;
    __syncthreads();
    sh[tid] += a;
    __syncthreads();
  }
  if (tid < nb) bsum[tid] = sh[tid] - v;   // exclusive block bases
  if (tid == 0) { off[nscan] = sh[127]; S[NTOT] = sh[127]; }
}

__global__ void scan_p3(int* __restrict__ data, const int* __restrict__ bsum, int n) {
  __shared__ int sh[256];
  int tid = threadIdx.x;
  int base = blockIdx.x * 4096 + tid * 16;
  int vals[16];
  int s = 0;
  #pragma unroll
  for (int j = 0; j < 16; j++) {
    vals[j] = (base + j < n) ? data[base + j] : 0;
    s += vals[j];
  }
  sh[tid] = s;
  __syncthreads();
  for (int o = 1; o < 256; o <<= 1) {
    int a = (tid >= o) ? sh[tid - o] : 0;
    __syncthreads();
    sh[tid] += a;
    __syncthreads();
  }
  int run = bsum[blockIdx.x] + sh[tid] - s;
  #pragma unroll
  for (int j = 0; j < 16; j++) {
    if (base + j < n) { data[base + j] = run; run += vals[j]; }
  }
}

// K3: replay chunk, LDS cursors from off matrix, write packed pairs
__global__ void scatter_ms(const int* __restrict__ s0, const int* __restrict__ s1,
                           const int* __restrict__ s2, const int* __restrict__ s3,
                           const int* __restrict__ d0, const int* __restrict__ d1,
                           const int* __restrict__ d2, const int* __restrict__ d3,
                           const int* __restrict__ off, unsigned int* __restrict__ pairs) {
  __shared__ int cur[NBUCK];
  int t = blockIdx.y, cx = blockIdx.x;
  int blk = t * CPE + cx;
  for (int i = threadIdx.x; i < NBUCK; i += 256)
    cur[i] = off[i * NBLKT + blk];
  __syncthreads();
  const int* sp = (t == 0) ? s0 : (t == 1) ? s1 : (t == 2) ? s2 : s3;
  const int* dp = (t == 0) ? d0 : (t == 1) ? d1 : (t == 2) ? d2 : d3;
  int base = cx * EPB2;
  int lim = base + EPB2; if (lim > EDGES) lim = EDGES;
  for (int i = base + threadIdx.x; i < lim; i += 256) {
    int key = t * NNODE + dp[i];
    int slot = atomicAdd(&cur[key >> BSH], 1);
    pairs[slot] = ((unsigned int)(key & 127) << 16) | (unsigned int)sp[i];
  }
}

// K4: per-bucket key sort -> CSR row pointers S + src list
__global__ void bucket_final(const int* __restrict__ off, const unsigned int* __restrict__ pairs,
                             int* __restrict__ S, int* __restrict__ srcs) {
  __shared__ int lcnt[128];
  __shared__ int loff[128];
  int b = blockIdx.x;
  int tid = threadIdx.x;
  int beg = off[b * NBLKT], end = off[(b + 1) * NBLKT];
  if (tid < 128) lcnt[tid] = 0;
  __syncthreads();
  for (int e = beg + tid; e < end; e += 256)
    atomicAdd(&lcnt[pairs[e] >> 16], 1);
  __syncthreads();
  int c = (tid < 128) ? lcnt[tid] : 0;
  if (tid < 128) loff[tid] = c;
  __syncthreads();
  for (int o = 1; o < 128; o <<= 1) {
    int a = (tid < 128 && tid >= o) ? loff[tid - o] : 0;
    __syncthreads();
    if (tid < 128) loff[tid] += a;
    __syncthreads();
  }
  if (tid < 128) {
    int ex = loff[tid] - c;
    int key = (b << BSH) + tid;
    if (key < NTOT) S[key] = beg + ex;
    lcnt[tid] = ex;                   // running cursor
  }
  __syncthreads();
  for (int e = beg + tid; e < end; e += 256) {
    unsigned int p = pairs[e];
    int lk = p >> 16;
    int slot = beg + atomicAdd(&lcnt[lk], 1);
    srcs[slot] = (int)(p & 0xFFFFu);
  }
}

// ---- aggregation: mean of src features per (etype, dst). Two etypes fused.
// Wave per dst: lanes split into 2 halves, each half owns alternating edges,
// u16x8 (16B) per lane, 1-ahead row prefetch, cross-half shfl reduce.
__device__ __forceinline__ void agg_loop(const int* __restrict__ srcs, int e0, int e1,
                                         int half, int l5,
                                         const unsigned short* __restrict__ feat, float* acc) {
  int e = e0 + half;
  u16x8 v = {};
  if (e < e1) v = *reinterpret_cast<const u16x8*>(feat + (size_t)srcs[e] * 256 + l5 * 8);
  while (e < e1) {
    u16x8 cur = v;
    e += 2;
    if (e < e1) v = *reinterpret_cast<const u16x8*>(feat + (size_t)srcs[e] * 256 + l5 * 8);
    #pragma unroll
    for (int j = 0; j < 8; j++) acc[j] += bf2f(cur[j]);
  }
}

__global__ __launch_bounds__(256) void agg_pair(
    const int* __restrict__ S, const int* __restrict__ srcs,
    const unsigned short* __restrict__ featA, int etA, unsigned short* __restrict__ outA,
    const unsigned short* __restrict__ featB, int etB, unsigned short* __restrict__ outB)
{
  int d = blockIdx.x * 4 + (threadIdx.x >> 6);
  int lane = threadIdx.x & 63;
  int half = lane >> 5, l5 = lane & 31;

  float accA[8] = {0,0,0,0,0,0,0,0}, accB[8] = {0,0,0,0,0,0,0,0};
  int gA = etA * NNODE + d;
  int a0 = S[gA], a1 = S[gA + 1];
  agg_loop(srcs, a0, a1, half, l5, featA, accA);
  int gB = etB * NNODE + d;
  int b0 = S[gB], b1 = S[gB + 1];
  agg_loop(srcs, b0, b1, half, l5, featB, accB);

  #pragma unroll
  for (int j = 0; j < 8; j++) {
    accA[j] += __shfl_xor(accA[j], 32);
    accB[j] += __shfl_xor(accB[j], 32);
  }
  float dA = (float)(a1 - a0); if (dA < 1.f) dA = 1.f;
  float dB = (float)(b1 - b0); if (dB < 1.f) dB = 1.f;
  float invA = 1.f / dA, invB = 1.f / dB;

  u16x8 o;
  if (half == 0) {
    #pragma unroll
    for (int j = 0; j < 8; j++) o[j] = f2bf(accA[j] * invA);
    *reinterpret_cast<u16x8*>(outA + (size_t)d * 256 + l5 * 8) = o;
  } else {
    #pragma unroll
    for (int j = 0; j < 8; j++) o[j] = f2bf(accB[j] * invB);
    *reinterpret_cast<u16x8*>(outB + (size_t)d * 256 + l5 * 8) = o;
  }
}

// ---- stacked-K GEMM: C = A0 @ W[0:256] + A1 @ W[256:512] (+ deg-masked biases)
// 64x64 tile, 4 waves x 32x32 quadrant, 16x16x32 MFMA, WT pre-transposed bf16 [256][512].
// MODE 0: leaky_relu + bf16 out. MODE 1: f32 out.
template<int MODE>
__global__ __launch_bounds__(256) void gemm512(
    const unsigned short* __restrict__ A0, const unsigned short* __restrict__ A1,
    const unsigned short* __restrict__ WT,
    const float* __restrict__ bA, const float* __restrict__ bB,
    const int* __restrict__ S, int etA, int etB,
    void* __restrict__ outp, int M)
{
  int tid = threadIdx.x;
  int m0 = blockIdx.x * 64, n0 = blockIdx.y * 64;
  int wave = tid >> 6, lane = tid & 63;
  int wr = wave >> 1, wc = wave & 1;
  int lrow = lane & 15, kgrp = lane >> 4;
  int rowbase = m0 + 32 * wr;

  f32x4 acc[2][2];
  #pragma unroll
  for (int a = 0; a < 2; a++)
    #pragma unroll
    for (int bq = 0; bq < 2; bq++) acc[a][bq] = (f32x4){0.f, 0.f, 0.f, 0.f};

  int r0 = rowbase + lrow;      if (r0 >= M) r0 = M - 1;
  int r1 = rowbase + 16 + lrow; if (r1 >= M) r1 = M - 1;
  const unsigned short* wrow0 = WT + (size_t)(n0 + 32 * wc + lrow) * 512 + kgrp * 8;
  const unsigned short* wrow1 = WT + (size_t)(n0 + 32 * wc + 16 + lrow) * 512 + kgrp * 8;

  {
    const unsigned short* xp0 = A0 + (size_t)r0 * 256 + kgrp * 8;
    const unsigned short* xp1 = A0 + (size_t)r1 * 256 + kgrp * 8;
    #pragma unroll
    for (int kk = 0; kk < 256; kk += 32) {
      bf16x8 a0 = *reinterpret_cast<const bf16x8*>(xp0 + kk);
      bf16x8 a1 = *reinterpret_cast<const bf16x8*>(xp1 + kk);
      bf16x8 b0 = *reinterpret_cast<const bf16x8*>(wrow0 + kk);
      bf16x8 b1 = *reinterpret_cast<const bf16x8*>(wrow1 + kk);
      acc[0][0] = __builtin_amdgcn_mfma_f32_16x16x32_bf16(a0, b0, acc[0][0], 0, 0, 0);
      acc[0][1] = __builtin_amdgcn_mfma_f32_16x16x32_bf16(a0, b1, acc[0][1], 0, 0, 0);
      acc[1][0] = __builtin_amdgcn_mfma_f32_16x16x32_bf16(a1, b0, acc[1][0], 0, 0, 0);
      acc[1][1] = __builtin_amdgcn_mfma_f32_16x16x32_bf16(a1, b1, acc[1][1], 0, 0, 0);
    }
  }
  {
    const unsigned short* xp0 = A1 + (size_t)r0 * 256 + kgrp * 8;
    const unsigned short* xp1 = A1 + (size_t)r1 * 256 + kgrp * 8;
    #pragma unroll
    for (int kk = 0; kk < 256; kk += 32) {
      bf16x8 a0 = *reinterpret_cast<const bf16x8*>(xp0 + kk);
      bf16x8 a1 = *reinterpret_cast<const bf16x8*>(xp1 + kk);
      bf16x8 b0 = *reinterpret_cast<const bf16x8*>(wrow0 + 256 + kk);
      bf16x8 b1 = *reinterpret_cast<const bf16x8*>(wrow1 + 256 + kk);
      acc[0][0] = __builtin_amdgcn_mfma_f32_16x16x32_bf16(a0, b0, acc[0][0], 0, 0, 0);
      acc[0][1] = __builtin_amdgcn_mfma_f32_16x16x32_bf16(a0, b1, acc[0][1], 0, 0, 0);
      acc[1][0] = __builtin_amdgcn_mfma_f32_16x16x32_bf16(a1, b0, acc[1][0], 0, 0, 0);
      acc[1][1] = __builtin_amdgcn_mfma_f32_16x16x32_bf16(a1, b1, acc[1][1], 0, 0, 0);
    }
  }

  // C/D layout: col = lane&15, row = (lane>>4)*4 + reg  [verified m89/m91]
  #pragma unroll
  for (int mb = 0; mb < 2; mb++) {
    #pragma unroll
    for (int r = 0; r < 4; r++) {
      int row = rowbase + 16 * mb + kgrp * 4 + r;
      if (row >= M) continue;
      int gA = etA * NNODE + row, gB = etB * NNODE + row;
      bool hA = S[gA + 1] > S[gA];   // deg>0: reference includes bias only via messages
      bool hB = S[gB + 1] > S[gB];
      #pragma unroll
      for (int nb = 0; nb < 2; nb++) {
        int col = n0 + 32 * wc + 16 * nb + lrow;
        float bias = (hA ? bA[col] : 0.f) + (hB ? bB[col] : 0.f);
        float v = acc[mb][nb][r] + bias;
        if (MODE == 0) {
          v = (v > 0.f) ? v : 0.01f * v;
          ((unsigned short*)outp)[(size_t)row * 256 + col] = f2bf(v);
        } else {
          ((float*)outp)[(size_t)row * 256 + col] = v;
        }
      }
    }
  }
}

extern "C" void kernel_launch(void* const* d_in, const int* in_sizes, int n_in,
                              void* d_out, int out_size, void* d_ws, size_t ws_size,
                              hipStream_t stream) {
  (void)in_sizes; (void)n_in;
  const float* chem = (const float*)d_in[0];
  const float* gene = (const float*)d_in[1];
  const float *W1[4], *B1[4], *W2[4], *B2[4];
  const int *SRC[4], *DST[4];
  // etype order: 0=ch2ge, 1=ge2ch, 2=ch2ch, 3=ge2ge
  for (int t = 0; t < 4; t++) {
    W1[t]  = (const float*)d_in[2 + 6 * t];
    B1[t]  = (const float*)d_in[3 + 6 * t];
    W2[t]  = (const float*)d_in[4 + 6 * t];
    B2[t]  = (const float*)d_in[5 + 6 * t];
    SRC[t] = (const int*)d_in[6 + 6 * t];
    DST[t] = (const int*)d_in[7 + 6 * t];
  }

  size_t off_b = 0;
  auto carve = [&](size_t bytes) -> void* {
    void* p = (char*)d_ws + off_b;
    off_b += (bytes + 255) & ~(size_t)255;
    return p;
  };
  const size_t FEAT_B = (size_t)NNODE * DIM * 2;  // 25.6 MB bf16
  unsigned short* xb_chem = (unsigned short*)carve(FEAT_B);
  unsigned short* xb_gene = (unsigned short*)carve(FEAT_B);
  unsigned short* h1_chem = (unsigned short*)carve(FEAT_B);
  unsigned short* h1_gene = (unsigned short*)carve(FEAT_B);
  unsigned short* aggA    = (unsigned short*)carve(FEAT_B);  // pairs+scan matrix aliased here
  unsigned short* aggB    = (unsigned short*)carve(FEAT_B);
  int* S    = (int*)carve(((size_t)NTOT + 1) * 4);
  int* srcs = (int*)carve((size_t)NET * EDGES * 4);
  unsigned short* WTc1 = (unsigned short*)carve((size_t)256 * 512 * 2);
  unsigned short* WTg1 = (unsigned short*)carve((size_t)256 * 512 * 2);
  unsigned short* WTc2 = (unsigned short*)carve((size_t)256 * 512 * 2);
  // aliases inside aggA (dead until after CSR build):
  unsigned int* pairs = (unsigned int*)aggA;                         // 6.4 MB
  int* cntoff = (int*)((char*)aggA + 6400000);                       // NSCAN+1 ints, in-place scan
  int* bsum   = cntoff + (NSCAN + 1);                                // 128 ints

  if (off_b > ws_size) {
    fill_f32<<<(out_size + 255) / 256, 256, 0, stream>>>((float*)d_out, (float)(ws_size >> 20), out_size);
    return;
  }

  int n4 = NNODE * DIM / 4;
  conv_f32_bf16<<<(n4 + 255) / 256, 256, 0, stream>>>(chem, xb_chem, n4);
  conv_f32_bf16<<<(n4 + 255) / 256, 256, 0, stream>>>(gene, xb_gene, n4);
  // stacked WTs: c1=(W1[1],W1[2]) c g1=(W1[0],W1[3]) c2=(W2[1],W2[2])
  conv_wT3<<<dim3(256, 3), 256, 0, stream>>>(W1[1], W1[2], W1[0], W1[3], W2[1], W2[2],
                                             WTc1, WTg1, WTc2);

  // ---- multi-split CSR build ----
  dim3 cgrid(CPE, 4);
  hist_ms<<<cgrid, 256, 0, stream>>>(DST[0], DST[1], DST[2], DST[3], cntoff);
  int nb1 = (NSCAN + 4095) / 4096;   // 75
  scan_p1<<<nb1, 256, 0, stream>>>(cntoff, bsum, NSCAN);
  scan_p2<<<1, 128, 0, stream>>>(bsum, nb1, cntoff, NSCAN, S);
  scan_p3<<<nb1, 256, 0, stream>>>(cntoff, bsum, NSCAN);
  scatter_ms<<<cgrid, 256, 0, stream>>>(SRC[0], SRC[1], SRC[2], SRC[3],
                                        DST[0], DST[1], DST[2], DST[3], cntoff, pairs);
  bucket_final<<<NBUCK, 256, 0, stream>>>(cntoff, pairs, S, srcs);

  dim3 ggrid((NNODE + 63) / 64, 4);
  int nagg = NNODE / 4;   // 12500 blocks x 4 waves
  // ---- layer 1, dt=chemical: et1 (src gene) + et2 (src chem)
  agg_pair<<<nagg, 256, 0, stream>>>(S, srcs, xb_gene, 1, aggA, xb_chem, 2, aggB);
  gemm512<0><<<ggrid, 256, 0, stream>>>(aggA, aggB, WTc1, B1[1], B1[2], S, 1, 2, h1_chem, NNODE);
  // ---- layer 1, dt=gene: et0 (src chem) + et3 (src gene)
  agg_pair<<<nagg, 256, 0, stream>>>(S, srcs, xb_chem, 0, aggA, xb_gene, 3, aggB);
  gemm512<0><<<ggrid, 256, 0, stream>>>(aggA, aggB, WTg1, B1[0], B1[3], S, 0, 3, h1_gene, NNODE);
  // ---- layer 2, dt=chemical only: et1 (src h1_gene) + et2 (src h1_chem)
  agg_pair<<<nagg, 256, 0, stream>>>(S, srcs, h1_gene, 1, aggA, h1_chem, 2, aggB);
  gemm512<1><<<ggrid, 256, 0, stream>>>(aggA, aggB, WTc2, B2[1], B2[2], S, 1, 2, d_out, NNODE);
}

// Round 4
// 599.916 us; speedup vs baseline: 1.5607x; 1.0453x over previous
//
#include <hip/hip_runtime.h>
#include <hip/hip_bf16.h>

#define NNODE 50000
#define DIM   256
#define EDGES 400000
#define NET   4
#define NTOT  (NET * NNODE)          // 200000
#define BSH   7
#define NBUCK ((NTOT + 127) >> BSH)  // 1563
#define EPB2  8192                   // edges per chunk
#define CPE   49                     // chunks per etype (49*8192 >= 400000)
#define NBLKT (CPE * NET)            // 196 chunk-blocks total
#define NSCAN (NBUCK * NBLKT)        // 306348

#define AS1 __attribute__((address_space(1)))
#define AS3 __attribute__((address_space(3)))

typedef __attribute__((ext_vector_type(8))) __bf16 bf16x8;
typedef __attribute__((ext_vector_type(4))) float f32x4;
typedef __attribute__((ext_vector_type(4))) unsigned short u16x4;
typedef __attribute__((ext_vector_type(8))) unsigned short u16x8;

__device__ __forceinline__ float bf2f(unsigned short u) {
  unsigned int x = ((unsigned int)u) << 16;
  return __builtin_bit_cast(float, x);
}
__device__ __forceinline__ unsigned short f2bf(float f) {
  __hip_bfloat16 h = __float2bfloat16(f);   // RTNE
  return __builtin_bit_cast(unsigned short, h);
}

__global__ void conv_f32_bf16(const float* __restrict__ in, unsigned short* __restrict__ out, int n4) {
  int i = blockIdx.x * blockDim.x + threadIdx.x;
  if (i >= n4) return;
  f32x4 v = reinterpret_cast<const f32x4*>(in)[i];
  u16x4 o;
  o[0] = f2bf(v[0]); o[1] = f2bf(v[1]); o[2] = f2bf(v[2]); o[3] = f2bf(v[3]);
  reinterpret_cast<u16x4*>(out)[i] = o;
}

// Build 3 stacked-K transposed weight matrices: T[n][k] with k<256 from A, k>=256 from B.
__global__ void conv_wT3(const float* __restrict__ a0, const float* __restrict__ b0,
                         const float* __restrict__ a1, const float* __restrict__ b1,
                         const float* __restrict__ a2, const float* __restrict__ b2,
                         unsigned short* __restrict__ t0, unsigned short* __restrict__ t1,
                         unsigned short* __restrict__ t2) {
  int m = blockIdx.y;
  const float* A = (m == 0) ? a0 : (m == 1) ? a1 : a2;
  const float* B = (m == 0) ? b0 : (m == 1) ? b1 : b2;
  unsigned short* T = (m == 0) ? t0 : (m == 1) ? t1 : t2;
  int n = blockIdx.x, k = threadIdx.x;   // 256 threads
  T[n * 512 + k]       = f2bf(A[k * 256 + n]);
  T[n * 512 + 256 + k] = f2bf(B[k * 256 + n]);
}

__global__ void fill_f32(float* __restrict__ p, float v, int n) {
  int i = blockIdx.x * blockDim.x + threadIdx.x;
  if (i < n) p[i] = v;
}

// ---- multi-split CSR build: no per-edge global atomics ----
__global__ void hist_ms(const int* __restrict__ d0, const int* __restrict__ d1,
                        const int* __restrict__ d2, const int* __restrict__ d3,
                        int* __restrict__ cnt) {
  __shared__ int h[NBUCK];
  for (int i = threadIdx.x; i < NBUCK; i += 256) h[i] = 0;
  __syncthreads();
  int t = blockIdx.y, cx = blockIdx.x;
  const int* dp = (t == 0) ? d0 : (t == 1) ? d1 : (t == 2) ? d2 : d3;
  int base = cx * EPB2;
  int lim = base + EPB2; if (lim > EDGES) lim = EDGES;
  for (int i = base + threadIdx.x; i < lim; i += 256)
    atomicAdd(&h[(t * NNODE + dp[i]) >> BSH], 1);
  __syncthreads();
  int blk = t * CPE + cx;
  for (int i = threadIdx.x; i < NBUCK; i += 256)
    cnt[i * NBLKT + blk] = h[i];
}

__global__ void scan_p1(const int* __restrict__ data, int* __restrict__ bsum, int n) {
  __shared__ int red[256];
  int base = blockIdx.x * 4096;
  int s = 0;
  #pragma unroll
  for (int j = 0; j < 16; j++) {
    int idx = base + j * 256 + threadIdx.x;
    s += (idx < n) ? data[idx] : 0;
  }
  red[threadIdx.x] = s;
  __syncthreads();
  for (int o = 128; o > 0; o >>= 1) {
    if (threadIdx.x < o) red[threadIdx.x] += red[threadIdx.x + o];
    __syncthreads();
  }
  if (threadIdx.x == 0) bsum[blockIdx.x] = red[0];
}

__global__ void scan_p2(int* __restrict__ bsum, int nb, int* __restrict__ off, int nscan,
                        int* __restrict__ S) {
  __shared__ int sh[128];
  int tid = threadIdx.x;
  int v = (tid < nb) ? bsum[tid] : 0;
  sh[tid] = v;
  __syncthreads();
  for (int o = 1; o < 128; o <<= 1) {
    int a = (tid >= o) ? sh[tid - o] : 0;
    __syncthreads();
    sh[tid] += a;
    __syncthreads();
  }
  if (tid < nb) bsum[tid] = sh[tid] - v;   // exclusive block bases
  if (tid == 0) { off[nscan] = sh[127]; S[NTOT] = sh[127]; }
}

__global__ void scan_p3(int* __restrict__ data, const int* __restrict__ bsum, int n) {
  __shared__ int sh[256];
  int tid = threadIdx.x;
  int base = blockIdx.x * 4096 + tid * 16;
  int vals[16];
  int s = 0;
  #pragma unroll
  for (int j = 0; j < 16; j++) {
    vals[j] = (base + j < n) ? data[base + j] : 0;
    s += vals[j];
  }
  sh[tid] = s;
  __syncthreads();
  for (int o = 1; o < 256; o <<= 1) {
    int a = (tid >= o) ? sh[tid - o] : 0;
    __syncthreads();
    sh[tid] += a;
    __syncthreads();
  }
  int run = bsum[blockIdx.x] + sh[tid] - s;
  #pragma unroll
  for (int j = 0; j < 16; j++) {
    if (base + j < n) { data[base + j] = run; run += vals[j]; }
  }
}

__global__ void scatter_ms(const int* __restrict__ s0, const int* __restrict__ s1,
                           const int* __restrict__ s2, const int* __restrict__ s3,
                           const int* __restrict__ d0, const int* __restrict__ d1,
                           const int* __restrict__ d2, const int* __restrict__ d3,
                           const int* __restrict__ off, unsigned int* __restrict__ pairs) {
  __shared__ int cur[NBUCK];
  int t = blockIdx.y, cx = blockIdx.x;
  int blk = t * CPE + cx;
  for (int i = threadIdx.x; i < NBUCK; i += 256)
    cur[i] = off[i * NBLKT + blk];
  __syncthreads();
  const int* sp = (t == 0) ? s0 : (t == 1) ? s1 : (t == 2) ? s2 : s3;
  const int* dp = (t == 0) ? d0 : (t == 1) ? d1 : (t == 2) ? d2 : d3;
  int base = cx * EPB2;
  int lim = base + EPB2; if (lim > EDGES) lim = EDGES;
  for (int i = base + threadIdx.x; i < lim; i += 256) {
    int key = t * NNODE + dp[i];
    int slot = atomicAdd(&cur[key >> BSH], 1);
    pairs[slot] = ((unsigned int)(key & 127) << 16) | (unsigned int)sp[i];
  }
}

__global__ void bucket_final(const int* __restrict__ off, const unsigned int* __restrict__ pairs,
                             int* __restrict__ S, int* __restrict__ srcs) {
  __shared__ int lcnt[128];
  __shared__ int loff[128];
  int b = blockIdx.x;
  int tid = threadIdx.x;
  int beg = off[b * NBLKT], end = off[(b + 1) * NBLKT];
  if (tid < 128) lcnt[tid] = 0;
  __syncthreads();
  for (int e = beg + tid; e < end; e += 256)
    atomicAdd(&lcnt[pairs[e] >> 16], 1);
  __syncthreads();
  int c = (tid < 128) ? lcnt[tid] : 0;
  if (tid < 128) loff[tid] = c;
  __syncthreads();
  for (int o = 1; o < 128; o <<= 1) {
    int a = (tid < 128 && tid >= o) ? loff[tid - o] : 0;
    __syncthreads();
    if (tid < 128) loff[tid] += a;
    __syncthreads();
  }
  if (tid < 128) {
    int ex = loff[tid] - c;
    int key = (b << BSH) + tid;
    if (key < NTOT) S[key] = beg + ex;
    lcnt[tid] = ex;                   // running cursor
  }
  __syncthreads();
  for (int e = beg + tid; e < end; e += 256) {
    unsigned int p = pairs[e];
    int lk = p >> 16;
    int slot = beg + atomicAdd(&lcnt[lk], 1);
    srcs[slot] = (int)(p & 0xFFFFu);
  }
}

// ---- aggregation: mean of src features per (etype, dst). Two etypes fused.
__device__ __forceinline__ void agg_loop(const int* __restrict__ srcs, int e0, int e1,
                                         int half, int l5,
                                         const unsigned short* __restrict__ feat, float* acc) {
  int e = e0 + half;
  u16x8 v = {};
  if (e < e1) v = *reinterpret_cast<const u16x8*>(feat + (size_t)srcs[e] * 256 + l5 * 8);
  while (e < e1) {
    u16x8 cur = v;
    e += 2;
    if (e < e1) v = *reinterpret_cast<const u16x8*>(feat + (size_t)srcs[e] * 256 + l5 * 8);
    #pragma unroll
    for (int j = 0; j < 8; j++) acc[j] += bf2f(cur[j]);
  }
}

__global__ __launch_bounds__(256) void agg_pair(
    const int* __restrict__ S, const int* __restrict__ srcs,
    const unsigned short* __restrict__ featA, int etA, unsigned short* __restrict__ outA,
    const unsigned short* __restrict__ featB, int etB, unsigned short* __restrict__ outB)
{
  int d = blockIdx.x * 4 + (threadIdx.x >> 6);
  int lane = threadIdx.x & 63;
  int half = lane >> 5, l5 = lane & 31;

  float accA[8] = {0,0,0,0,0,0,0,0}, accB[8] = {0,0,0,0,0,0,0,0};
  int gA = etA * NNODE + d;
  int a0 = S[gA], a1 = S[gA + 1];
  agg_loop(srcs, a0, a1, half, l5, featA, accA);
  int gB = etB * NNODE + d;
  int b0 = S[gB], b1 = S[gB + 1];
  agg_loop(srcs, b0, b1, half, l5, featB, accB);

  #pragma unroll
  for (int j = 0; j < 8; j++) {
    accA[j] += __shfl_xor(accA[j], 32);
    accB[j] += __shfl_xor(accB[j], 32);
  }
  float dA = (float)(a1 - a0); if (dA < 1.f) dA = 1.f;
  float dB = (float)(b1 - b0); if (dB < 1.f) dB = 1.f;
  float invA = 1.f / dA, invB = 1.f / dB;

  u16x8 o;
  if (half == 0) {
    #pragma unroll
    for (int j = 0; j < 8; j++) o[j] = f2bf(accA[j] * invA);
    *reinterpret_cast<u16x8*>(outA + (size_t)d * 256 + l5 * 8) = o;
  } else {
    #pragma unroll
    for (int j = 0; j < 8; j++) o[j] = f2bf(accB[j] * invB);
    *reinterpret_cast<u16x8*>(outB + (size_t)d * 256 + l5 * 8) = o;
  }
}

// ---- stacked-K GEMM v2: C = [A0|A1](bf16 50000x512) @ WT^T + deg-masked biases.
// Block: 64 rows x 256 cols (full N), grid = 782. K=512 in 8 chunks of 64,
// A staged to LDS via global_load_lds (16B) with XOR-swizzled source (T2 + rule 21),
// double-buffered, 2-phase pipeline. 4 waves x (32 rows x 128 cols), acc[2][8].
// B read direct from L2-resident WT. MODE 0: leaky_relu + bf16. MODE 1: f32.
template<int MODE>
__global__ __launch_bounds__(256) void gemm512(
    const unsigned short* __restrict__ A0, const unsigned short* __restrict__ A1,
    const unsigned short* __restrict__ WT,
    const float* __restrict__ bA, const float* __restrict__ bB,
    const int* __restrict__ S, int etA, int etB,
    void* __restrict__ outp, int M)
{
  __shared__ unsigned short abuf[2][64 * 64];   // 2 x 8KB, row stride 128B, swizzled
  int tid = threadIdx.x;
  int m0 = blockIdx.x * 64;
  int wave = tid >> 6, lane = tid & 63;
  int wr = wave >> 1, wc = wave & 1;
  int lrow = lane & 15, kgrp = lane >> 4;

  // staging geometry (per thread, both issues)
  int ld_wbase = wave << 10;                 // wave-uniform LDS byte base
  int ld_row0 = tid >> 3;                    // issue 0 row (0..31); issue 1 adds 32
  int ld_kb0 = ((tid & 7) << 4) ^ ((ld_row0 & 7) << 4);   // inverse-swizzled source col byte

  f32x4 acc[2][8];
  #pragma unroll
  for (int a = 0; a < 2; a++)
    #pragma unroll
    for (int b = 0; b < 8; b++) acc[a][b] = (f32x4){0.f, 0.f, 0.f, 0.f};

  // hoisted B row pointers (WT row stride = 512 bf16)
  const unsigned short* wbase[8];
  #pragma unroll
  for (int nb = 0; nb < 8; nb++)
    wbase[nb] = WT + (size_t)(128 * wc + 16 * nb + lrow) * 512 + kgrp * 8;

  auto stage = [&](int ck) {
    const unsigned short* Asrc = (ck < 4) ? A0 : A1;
    int ckk = ck & 3;
    char* dst = (char*)&abuf[ck & 1][0] + ld_wbase;
    #pragma unroll
    for (int iss = 0; iss < 2; iss++) {
      int row = iss * 32 + ld_row0;
      const char* src = (const char*)Asrc + (size_t)(m0 + row) * 512 + ckk * 128 + ld_kb0;
      __builtin_amdgcn_global_load_lds(
          (const AS1 unsigned int*)(const void*)src,
          (AS3 unsigned int*)(void*)(dst + iss * 4096), 16, 0, 0);
    }
  };

  stage(0);
  asm volatile("s_waitcnt vmcnt(0)" ::: "memory");
  __syncthreads();

  int r0 = 32 * wr + lrow;
  int r1 = r0 + 16;
  int sw0 = (r0 & 7) << 4;                    // == (r1&7)<<4
  for (int ck = 0; ck < 8; ck++) {
    if (ck < 7) stage(ck + 1);
    const char* bufp = (const char*)&abuf[ck & 1][0];
    int kbase = ck * 64;                      // global k offset (bf16 units)
    #pragma unroll
    for (int ks = 0; ks < 2; ks++) {
      bf16x8 bfr[8];
      #pragma unroll
      for (int nb = 0; nb < 8; nb++)
        bfr[nb] = *reinterpret_cast<const bf16x8*>(wbase[nb] + kbase + ks * 32);
      int kb = (ks * 64 + kgrp * 16);
      bf16x8 a0 = *reinterpret_cast<const bf16x8*>(bufp + r0 * 128 + (kb ^ sw0));
      bf16x8 a1 = *reinterpret_cast<const bf16x8*>(bufp + r1 * 128 + (kb ^ sw0));
      #pragma unroll
      for (int nb = 0; nb < 8; nb++) {
        acc[0][nb] = __builtin_amdgcn_mfma_f32_16x16x32_bf16(a0, bfr[nb], acc[0][nb], 0, 0, 0);
        acc[1][nb] = __builtin_amdgcn_mfma_f32_16x16x32_bf16(a1, bfr[nb], acc[1][nb], 0, 0, 0);
      }
    }
    asm volatile("s_waitcnt vmcnt(0)" ::: "memory");
    __syncthreads();
  }

  // C/D layout: col = lane&15, row = (lane>>4)*4 + reg  [verified m89/m91]
  #pragma unroll
  for (int mb = 0; mb < 2; mb++) {
    #pragma unroll
    for (int r = 0; r < 4; r++) {
      int row = m0 + 32 * wr + 16 * mb + kgrp * 4 + r;
      if (row >= M) continue;
      int gA = etA * NNODE + row, gB = etB * NNODE + row;
      bool hA = S[gA + 1] > S[gA];   // deg>0: bias enters only via messages
      bool hB = S[gB + 1] > S[gB];
      #pragma unroll
      for (int nb = 0; nb < 8; nb++) {
        int col = 128 * wc + 16 * nb + lrow;
        float bias = (hA ? bA[col] : 0.f) + (hB ? bB[col] : 0.f);
        float v = acc[mb][nb][r] + bias;
        if (MODE == 0) {
          v = (v > 0.f) ? v : 0.01f * v;
          ((unsigned short*)outp)[(size_t)row * 256 + col] = f2bf(v);
        } else {
          ((float*)outp)[(size_t)row * 256 + col] = v;
        }
      }
    }
  }
}

extern "C" void kernel_launch(void* const* d_in, const int* in_sizes, int n_in,
                              void* d_out, int out_size, void* d_ws, size_t ws_size,
                              hipStream_t stream) {
  (void)in_sizes; (void)n_in;
  const float* chem = (const float*)d_in[0];
  const float* gene = (const float*)d_in[1];
  const float *W1[4], *B1[4], *W2[4], *B2[4];
  const int *SRC[4], *DST[4];
  // etype order: 0=ch2ge, 1=ge2ch, 2=ch2ch, 3=ge2ge
  for (int t = 0; t < 4; t++) {
    W1[t]  = (const float*)d_in[2 + 6 * t];
    B1[t]  = (const float*)d_in[3 + 6 * t];
    W2[t]  = (const float*)d_in[4 + 6 * t];
    B2[t]  = (const float*)d_in[5 + 6 * t];
    SRC[t] = (const int*)d_in[6 + 6 * t];
    DST[t] = (const int*)d_in[7 + 6 * t];
  }

  size_t off_b = 0;
  auto carve = [&](size_t bytes) -> void* {
    void* p = (char*)d_ws + off_b;
    off_b += (bytes + 255) & ~(size_t)255;
    return p;
  };
  const size_t FEAT_B = (size_t)NNODE * DIM * 2;  // 25.6 MB bf16
  unsigned short* xb_chem = (unsigned short*)carve(FEAT_B);
  unsigned short* xb_gene = (unsigned short*)carve(FEAT_B);
  unsigned short* h1_chem = (unsigned short*)carve(FEAT_B);
  unsigned short* h1_gene = (unsigned short*)carve(FEAT_B);
  unsigned short* aggA    = (unsigned short*)carve(FEAT_B);  // pairs+scan matrix aliased here
  unsigned short* aggB    = (unsigned short*)carve(FEAT_B);
  int* S    = (int*)carve(((size_t)NTOT + 1) * 4);
  int* srcs = (int*)carve((size_t)NET * EDGES * 4);
  unsigned short* WTc1 = (unsigned short*)carve((size_t)256 * 512 * 2);
  unsigned short* WTg1 = (unsigned short*)carve((size_t)256 * 512 * 2);
  unsigned short* WTc2 = (unsigned short*)carve((size_t)256 * 512 * 2);
  // aliases inside aggA (dead until after CSR build):
  unsigned int* pairs = (unsigned int*)aggA;                         // 6.4 MB
  int* cntoff = (int*)((char*)aggA + 6400000);                       // NSCAN+1 ints, in-place scan
  int* bsum   = cntoff + (NSCAN + 1);                                // 128 ints

  if (off_b > ws_size) {
    fill_f32<<<(out_size + 255) / 256, 256, 0, stream>>>((float*)d_out, (float)(ws_size >> 20), out_size);
    return;
  }

  int n4 = NNODE * DIM / 4;
  conv_f32_bf16<<<(n4 + 255) / 256, 256, 0, stream>>>(chem, xb_chem, n4);
  conv_f32_bf16<<<(n4 + 255) / 256, 256, 0, stream>>>(gene, xb_gene, n4);
  // stacked WTs: c1=(W1[1],W1[2])  g1=(W1[0],W1[3])  c2=(W2[1],W2[2])
  conv_wT3<<<dim3(256, 3), 256, 0, stream>>>(W1[1], W1[2], W1[0], W1[3], W2[1], W2[2],
                                             WTc1, WTg1, WTc2);

  // ---- multi-split CSR build ----
  dim3 cgrid(CPE, 4);
  hist_ms<<<cgrid, 256, 0, stream>>>(DST[0], DST[1], DST[2], DST[3], cntoff);
  int nb1 = (NSCAN + 4095) / 4096;   // 75
  scan_p1<<<nb1, 256, 0, stream>>>(cntoff, bsum, NSCAN);
  scan_p2<<<1, 128, 0, stream>>>(bsum, nb1, cntoff, NSCAN, S);
  scan_p3<<<nb1, 256, 0, stream>>>(cntoff, bsum, NSCAN);
  scatter_ms<<<cgrid, 256, 0, stream>>>(SRC[0], SRC[1], SRC[2], SRC[3],
                                        DST[0], DST[1], DST[2], DST[3], cntoff, pairs);
  bucket_final<<<NBUCK, 256, 0, stream>>>(cntoff, pairs, S, srcs);

  dim3 ggrid2((NNODE + 63) / 64);   // 782 blocks, full-N per block
  int nagg = NNODE / 4;             // 12500 blocks x 4 waves
  // ---- layer 1, dt=chemical: et1 (src gene) + et2 (src chem)
  agg_pair<<<nagg, 256, 0, stream>>>(S, srcs, xb_gene, 1, aggA, xb_chem, 2, aggB);
  gemm512<0><<<ggrid2, 256, 0, stream>>>(aggA, aggB, WTc1, B1[1], B1[2], S, 1, 2, h1_chem, NNODE);
  // ---- layer 1, dt=gene: et0 (src chem) + et3 (src gene)
  agg_pair<<<nagg, 256, 0, stream>>>(S, srcs, xb_chem, 0, aggA, xb_gene, 3, aggB);
  gemm512<0><<<ggrid2, 256, 0, stream>>>(aggA, aggB, WTg1, B1[0], B1[3], S, 0, 3, h1_gene, NNODE);
  // ---- layer 2, dt=chemical only: et1 (src h1_gene) + et2 (src h1_chem)
  agg_pair<<<nagg, 256, 0, stream>>>(S, srcs, h1_gene, 1, aggA, h1_chem, 2, aggB);
  gemm512<1><<<ggrid2, 256, 0, stream>>>(aggA, aggB, WTc2, B2[1], B2[2], S, 1, 2, d_out, NNODE);
}

// Round 5
// 568.478 us; speedup vs baseline: 1.6470x; 1.0553x over previous
//
#include <hip/hip_runtime.h>
#include <hip/hip_bf16.h>

#define NNODE 50000
#define DIM   256
#define EDGES 400000
#define NET   4
#define NTOT  (NET * NNODE)          // 200000
#define BSH   7
#define NBUCK ((NTOT + 127) >> BSH)  // 1563
#define EPB2  8192                   // edges per chunk
#define CPE   49                     // chunks per etype (49*8192 >= 400000)
#define NBLKT (CPE * NET)            // 196 chunk-blocks total
#define NSCAN (NBUCK * NBLKT)        // 306348

typedef __attribute__((ext_vector_type(8))) __bf16 bf16x8;
typedef __attribute__((ext_vector_type(4))) float f32x4;
typedef __attribute__((ext_vector_type(4))) unsigned short u16x4;
typedef __attribute__((ext_vector_type(8))) unsigned short u16x8;

__device__ __forceinline__ float bf2f(unsigned short u) {
  unsigned int x = ((unsigned int)u) << 16;
  return __builtin_bit_cast(float, x);
}
__device__ __forceinline__ unsigned short f2bf(float f) {
  __hip_bfloat16 h = __float2bfloat16(f);   // RTNE
  return __builtin_bit_cast(unsigned short, h);
}

__global__ void conv_f32_bf16(const float* __restrict__ in, unsigned short* __restrict__ out, int n4) {
  int i = blockIdx.x * blockDim.x + threadIdx.x;
  if (i >= n4) return;
  f32x4 v = reinterpret_cast<const f32x4*>(in)[i];
  u16x4 o;
  o[0] = f2bf(v[0]); o[1] = f2bf(v[1]); o[2] = f2bf(v[2]); o[3] = f2bf(v[3]);
  reinterpret_cast<u16x4*>(out)[i] = o;
}

// Build 3 stacked-K transposed weight matrices: T[n][k] with k<256 from A, k>=256 from B.
__global__ void conv_wT3(const float* __restrict__ a0, const float* __restrict__ b0,
                         const float* __restrict__ a1, const float* __restrict__ b1,
                         const float* __restrict__ a2, const float* __restrict__ b2,
                         unsigned short* __restrict__ t0, unsigned short* __restrict__ t1,
                         unsigned short* __restrict__ t2) {
  int m = blockIdx.y;
  const float* A = (m == 0) ? a0 : (m == 1) ? a1 : a2;
  const float* B = (m == 0) ? b0 : (m == 1) ? b1 : b2;
  unsigned short* T = (m == 0) ? t0 : (m == 1) ? t1 : t2;
  int n = blockIdx.x, k = threadIdx.x;   // 256 threads
  T[n * 512 + k]       = f2bf(A[k * 256 + n]);
  T[n * 512 + 256 + k] = f2bf(B[k * 256 + n]);
}

__global__ void fill_f32(float* __restrict__ p, float v, int n) {
  int i = blockIdx.x * blockDim.x + threadIdx.x;
  if (i < n) p[i] = v;
}

// ---- multi-split CSR build: no per-edge global atomics ----
__global__ void hist_ms(const int* __restrict__ d0, const int* __restrict__ d1,
                        const int* __restrict__ d2, const int* __restrict__ d3,
                        int* __restrict__ cnt) {
  __shared__ int h[NBUCK];
  for (int i = threadIdx.x; i < NBUCK; i += 256) h[i] = 0;
  __syncthreads();
  int t = blockIdx.y, cx = blockIdx.x;
  const int* dp = (t == 0) ? d0 : (t == 1) ? d1 : (t == 2) ? d2 : d3;
  int base = cx * EPB2;
  int lim = base + EPB2; if (lim > EDGES) lim = EDGES;
  for (int i = base + threadIdx.x; i < lim; i += 256)
    atomicAdd(&h[(t * NNODE + dp[i]) >> BSH], 1);
  __syncthreads();
  int blk = t * CPE + cx;
  for (int i = threadIdx.x; i < NBUCK; i += 256)
    cnt[i * NBLKT + blk] = h[i];
}

__global__ void scan_p1(const int* __restrict__ data, int* __restrict__ bsum, int n) {
  __shared__ int red[256];
  int base = blockIdx.x * 4096;
  int s = 0;
  #pragma unroll
  for (int j = 0; j < 16; j++) {
    int idx = base + j * 256 + threadIdx.x;
    s += (idx < n) ? data[idx] : 0;
  }
  red[threadIdx.x] = s;
  __syncthreads();
  for (int o = 128; o > 0; o >>= 1) {
    if (threadIdx.x < o) red[threadIdx.x] += red[threadIdx.x + o];
    __syncthreads();
  }
  if (threadIdx.x == 0) bsum[blockIdx.x] = red[0];
}

__global__ void scan_p2(int* __restrict__ bsum, int nb, int* __restrict__ off, int nscan,
                        int* __restrict__ S) {
  __shared__ int sh[128];
  int tid = threadIdx.x;
  int v = (tid < nb) ? bsum[tid] : 0;
  sh[tid] = v;
  __syncthreads();
  for (int o = 1; o < 128; o <<= 1) {
    int a = (tid >= o) ? sh[tid - o] : 0;
    __syncthreads();
    sh[tid] += a;
    __syncthreads();
  }
  if (tid < nb) bsum[tid] = sh[tid] - v;   // exclusive block bases
  if (tid == 0) { off[nscan] = sh[127]; S[NTOT] = sh[127]; }
}

__global__ void scan_p3(int* __restrict__ data, const int* __restrict__ bsum, int n) {
  __shared__ int sh[256];
  int tid = threadIdx.x;
  int base = blockIdx.x * 4096 + tid * 16;
  int vals[16];
  int s = 0;
  #pragma unroll
  for (int j = 0; j < 16; j++) {
    vals[j] = (base + j < n) ? data[base + j] : 0;
    s += vals[j];
  }
  sh[tid] = s;
  __syncthreads();
  for (int o = 1; o < 256; o <<= 1) {
    int a = (tid >= o) ? sh[tid - o] : 0;
    __syncthreads();
    sh[tid] += a;
    __syncthreads();
  }
  int run = bsum[blockIdx.x] + sh[tid] - s;
  #pragma unroll
  for (int j = 0; j < 16; j++) {
    if (base + j < n) { data[base + j] = run; run += vals[j]; }
  }
}

__global__ void scatter_ms(const int* __restrict__ s0, const int* __restrict__ s1,
                           const int* __restrict__ s2, const int* __restrict__ s3,
                           const int* __restrict__ d0, const int* __restrict__ d1,
                           const int* __restrict__ d2, const int* __restrict__ d3,
                           const int* __restrict__ off, unsigned int* __restrict__ pairs) {
  __shared__ int cur[NBUCK];
  int t = blockIdx.y, cx = blockIdx.x;
  int blk = t * CPE + cx;
  for (int i = threadIdx.x; i < NBUCK; i += 256)
    cur[i] = off[i * NBLKT + blk];
  __syncthreads();
  const int* sp = (t == 0) ? s0 : (t == 1) ? s1 : (t == 2) ? s2 : s3;
  const int* dp = (t == 0) ? d0 : (t == 1) ? d1 : (t == 2) ? d2 : d3;
  int base = cx * EPB2;
  int lim = base + EPB2; if (lim > EDGES) lim = EDGES;
  for (int i = base + threadIdx.x; i < lim; i += 256) {
    int key = t * NNODE + dp[i];
    int slot = atomicAdd(&cur[key >> BSH], 1);
    pairs[slot] = ((unsigned int)(key & 127) << 16) | (unsigned int)sp[i];
  }
}

__global__ void bucket_final(const int* __restrict__ off, const unsigned int* __restrict__ pairs,
                             int* __restrict__ S, int* __restrict__ srcs) {
  __shared__ int lcnt[128];
  __shared__ int loff[128];
  int b = blockIdx.x;
  int tid = threadIdx.x;
  int beg = off[b * NBLKT], end = off[(b + 1) * NBLKT];
  if (tid < 128) lcnt[tid] = 0;
  __syncthreads();
  for (int e = beg + tid; e < end; e += 256)
    atomicAdd(&lcnt[pairs[e] >> 16], 1);
  __syncthreads();
  int c = (tid < 128) ? lcnt[tid] : 0;
  if (tid < 128) loff[tid] = c;
  __syncthreads();
  for (int o = 1; o < 128; o <<= 1) {
    int a = (tid < 128 && tid >= o) ? loff[tid - o] : 0;
    __syncthreads();
    if (tid < 128) loff[tid] += a;
    __syncthreads();
  }
  if (tid < 128) {
    int ex = loff[tid] - c;
    int key = (b << BSH) + tid;
    if (key < NTOT) S[key] = beg + ex;
    lcnt[tid] = ex;                   // running cursor
  }
  __syncthreads();
  for (int e = beg + tid; e < end; e += 256) {
    unsigned int p = pairs[e];
    int lk = p >> 16;
    int slot = beg + atomicAdd(&lcnt[lk], 1);
    srcs[slot] = (int)(p & 0xFFFFu);
  }
}

// ---- aggregation: mean of src features per (etype, dst). Two etypes fused.
__device__ __forceinline__ void agg_loop(const int* __restrict__ srcs, int e0, int e1,
                                         int half, int l5,
                                         const unsigned short* __restrict__ feat, float* acc) {
  int e = e0 + half;
  u16x8 v = {};
  if (e < e1) v = *reinterpret_cast<const u16x8*>(feat + (size_t)srcs[e] * 256 + l5 * 8);
  while (e < e1) {
    u16x8 cur = v;
    e += 2;
    if (e < e1) v = *reinterpret_cast<const u16x8*>(feat + (size_t)srcs[e] * 256 + l5 * 8);
    #pragma unroll
    for (int j = 0; j < 8; j++) acc[j] += bf2f(cur[j]);
  }
}

__global__ __launch_bounds__(256) void agg_pair(
    const int* __restrict__ S, const int* __restrict__ srcs,
    const unsigned short* __restrict__ featA, int etA, unsigned short* __restrict__ outA,
    const unsigned short* __restrict__ featB, int etB, unsigned short* __restrict__ outB)
{
  int d = blockIdx.x * 4 + (threadIdx.x >> 6);
  int lane = threadIdx.x & 63;
  int half = lane >> 5, l5 = lane & 31;

  float accA[8] = {0,0,0,0,0,0,0,0}, accB[8] = {0,0,0,0,0,0,0,0};
  int gA = etA * NNODE + d;
  int a0 = S[gA], a1 = S[gA + 1];
  agg_loop(srcs, a0, a1, half, l5, featA, accA);
  int gB = etB * NNODE + d;
  int b0 = S[gB], b1 = S[gB + 1];
  agg_loop(srcs, b0, b1, half, l5, featB, accB);

  #pragma unroll
  for (int j = 0; j < 8; j++) {
    accA[j] += __shfl_xor(accA[j], 32);
    accB[j] += __shfl_xor(accB[j], 32);
  }
  float dA = (float)(a1 - a0); if (dA < 1.f) dA = 1.f;
  float dB = (float)(b1 - b0); if (dB < 1.f) dB = 1.f;
  float invA = 1.f / dA, invB = 1.f / dB;

  u16x8 o;
  if (half == 0) {
    #pragma unroll
    for (int j = 0; j < 8; j++) o[j] = f2bf(accA[j] * invA);
    *reinterpret_cast<u16x8*>(outA + (size_t)d * 256 + l5 * 8) = o;
  } else {
    #pragma unroll
    for (int j = 0; j < 8; j++) o[j] = f2bf(accB[j] * invB);
    *reinterpret_cast<u16x8*>(outB + (size_t)d * 256 + l5 * 8) = o;
  }
}

// ---- stacked-K GEMM v3: C = [A0|A1](bf16 50000x512) @ WT^T + deg-masked biases.
// Pure register pipeline, no LDS, no barriers. Block: 64 rows x 256 cols, grid 782.
// 4 waves x (32 rows x 128 cols), acc[2][8]. K fully unrolled (16 steps of 32) with
// explicit 1-step-ahead prefetch into named registers -> ~10 loads in flight per wave.
// B read direct from L2-resident WT. MODE 0: leaky_relu + bf16. MODE 1: f32.
template<int MODE>
__global__ __launch_bounds__(256, 2) void gemm512(
    const unsigned short* __restrict__ A0, const unsigned short* __restrict__ A1,
    const unsigned short* __restrict__ WT,
    const float* __restrict__ bA, const float* __restrict__ bB,
    const int* __restrict__ S, int etA, int etB,
    void* __restrict__ outp, int M)
{
  int tid = threadIdx.x;
  int m0 = blockIdx.x * 64;
  int wave = tid >> 6, lane = tid & 63;
  int wr = wave >> 1, wc = wave & 1;
  int lrow = lane & 15, kgrp = lane >> 4;

  f32x4 acc[2][8];
  #pragma unroll
  for (int a = 0; a < 2; a++)
    #pragma unroll
    for (int b = 0; b < 8; b++) acc[a][b] = (f32x4){0.f, 0.f, 0.f, 0.f};

  int r0 = m0 + 32 * wr + lrow;      if (r0 >= M) r0 = M - 1;
  int r1 = m0 + 32 * wr + 16 + lrow; if (r1 >= M) r1 = M - 1;

  // B row pointers (WT row stride = 512 bf16); kgrp offset folded in.
  const unsigned short* wb[8];
  #pragma unroll
  for (int nb = 0; nb < 8; nb++)
    wb[nb] = WT + (size_t)(128 * wc + 16 * nb + lrow) * 512 + kgrp * 8;

#define LOADS(KS, A0V, A1V, BV)                                              \
  {                                                                          \
    const unsigned short* Ab = ((KS) < 8) ? A0 : A1;                         \
    int cc = ((KS) & 7) * 32 + kgrp * 8;                                     \
    A0V = *reinterpret_cast<const bf16x8*>(Ab + (size_t)r0 * 256 + cc);      \
    A1V = *reinterpret_cast<const bf16x8*>(Ab + (size_t)r1 * 256 + cc);      \
    for (int nb = 0; nb < 8; nb++)                                           \
      BV[nb] = *reinterpret_cast<const bf16x8*>(wb[nb] + (KS) * 32);         \
  }

  bf16x8 a0c, a1c, bc[8];
  LOADS(0, a0c, a1c, bc);
  #pragma unroll
  for (int ks = 0; ks < 16; ks++) {
    bf16x8 a0n, a1n, bn[8];
    if (ks < 15) LOADS(ks + 1, a0n, a1n, bn);
    #pragma unroll
    for (int nb = 0; nb < 8; nb++) {
      acc[0][nb] = __builtin_amdgcn_mfma_f32_16x16x32_bf16(a0c, bc[nb], acc[0][nb], 0, 0, 0);
      acc[1][nb] = __builtin_amdgcn_mfma_f32_16x16x32_bf16(a1c, bc[nb], acc[1][nb], 0, 0, 0);
    }
    if (ks < 15) {
      a0c = a0n; a1c = a1n;
      #pragma unroll
      for (int nb = 0; nb < 8; nb++) bc[nb] = bn[nb];
    }
  }
#undef LOADS

  // C/D layout: col = lane&15, row = (lane>>4)*4 + reg  [verified m89/m91]
  #pragma unroll
  for (int mb = 0; mb < 2; mb++) {
    #pragma unroll
    for (int r = 0; r < 4; r++) {
      int row = m0 + 32 * wr + 16 * mb + kgrp * 4 + r;
      if (row >= M) continue;
      int gA = etA * NNODE + row, gB = etB * NNODE + row;
      bool hA = S[gA + 1] > S[gA];   // deg>0: bias enters only via messages
      bool hB = S[gB + 1] > S[gB];
      #pragma unroll
      for (int nb = 0; nb < 8; nb++) {
        int col = 128 * wc + 16 * nb + lrow;
        float bias = (hA ? bA[col] : 0.f) + (hB ? bB[col] : 0.f);
        float v = acc[mb][nb][r] + bias;
        if (MODE == 0) {
          v = (v > 0.f) ? v : 0.01f * v;
          ((unsigned short*)outp)[(size_t)row * 256 + col] = f2bf(v);
        } else {
          ((float*)outp)[(size_t)row * 256 + col] = v;
        }
      }
    }
  }
}

extern "C" void kernel_launch(void* const* d_in, const int* in_sizes, int n_in,
                              void* d_out, int out_size, void* d_ws, size_t ws_size,
                              hipStream_t stream) {
  (void)in_sizes; (void)n_in;
  const float* chem = (const float*)d_in[0];
  const float* gene = (const float*)d_in[1];
  const float *W1[4], *B1[4], *W2[4], *B2[4];
  const int *SRC[4], *DST[4];
  // etype order: 0=ch2ge, 1=ge2ch, 2=ch2ch, 3=ge2ge
  for (int t = 0; t < 4; t++) {
    W1[t]  = (const float*)d_in[2 + 6 * t];
    B1[t]  = (const float*)d_in[3 + 6 * t];
    W2[t]  = (const float*)d_in[4 + 6 * t];
    B2[t]  = (const float*)d_in[5 + 6 * t];
    SRC[t] = (const int*)d_in[6 + 6 * t];
    DST[t] = (const int*)d_in[7 + 6 * t];
  }

  size_t off_b = 0;
  auto carve = [&](size_t bytes) -> void* {
    void* p = (char*)d_ws + off_b;
    off_b += (bytes + 255) & ~(size_t)255;
    return p;
  };
  const size_t FEAT_B = (size_t)NNODE * DIM * 2;  // 25.6 MB bf16
  unsigned short* xb_chem = (unsigned short*)carve(FEAT_B);
  unsigned short* xb_gene = (unsigned short*)carve(FEAT_B);
  unsigned short* h1_chem = (unsigned short*)carve(FEAT_B);
  unsigned short* h1_gene = (unsigned short*)carve(FEAT_B);
  unsigned short* aggA    = (unsigned short*)carve(FEAT_B);  // pairs+scan matrix aliased here
  unsigned short* aggB    = (unsigned short*)carve(FEAT_B);
  int* S    = (int*)carve(((size_t)NTOT + 1) * 4);
  int* srcs = (int*)carve((size_t)NET * EDGES * 4);
  unsigned short* WTc1 = (unsigned short*)carve((size_t)256 * 512 * 2);
  unsigned short* WTg1 = (unsigned short*)carve((size_t)256 * 512 * 2);
  unsigned short* WTc2 = (unsigned short*)carve((size_t)256 * 512 * 2);
  // aliases inside aggA (dead until after CSR build):
  unsigned int* pairs = (unsigned int*)aggA;                         // 6.4 MB
  int* cntoff = (int*)((char*)aggA + 6400000);                       // NSCAN+1 ints, in-place scan
  int* bsum   = cntoff + (NSCAN + 1);                                // 128 ints

  if (off_b > ws_size) {
    fill_f32<<<(out_size + 255) / 256, 256, 0, stream>>>((float*)d_out, (float)(ws_size >> 20), out_size);
    return;
  }

  int n4 = NNODE * DIM / 4;
  conv_f32_bf16<<<(n4 + 255) / 256, 256, 0, stream>>>(chem, xb_chem, n4);
  conv_f32_bf16<<<(n4 + 255) / 256, 256, 0, stream>>>(gene, xb_gene, n4);
  // stacked WTs: c1=(W1[1],W1[2])  g1=(W1[0],W1[3])  c2=(W2[1],W2[2])
  conv_wT3<<<dim3(256, 3), 256, 0, stream>>>(W1[1], W1[2], W1[0], W1[3], W2[1], W2[2],
                                             WTc1, WTg1, WTc2);

  // ---- multi-split CSR build ----
  dim3 cgrid(CPE, 4);
  hist_ms<<<cgrid, 256, 0, stream>>>(DST[0], DST[1], DST[2], DST[3], cntoff);
  int nb1 = (NSCAN + 4095) / 4096;   // 75
  scan_p1<<<nb1, 256, 0, stream>>>(cntoff, bsum, NSCAN);
  scan_p2<<<1, 128, 0, stream>>>(bsum, nb1, cntoff, NSCAN, S);
  scan_p3<<<nb1, 256, 0, stream>>>(cntoff, bsum, NSCAN);
  scatter_ms<<<cgrid, 256, 0, stream>>>(SRC[0], SRC[1], SRC[2], SRC[3],
                                        DST[0], DST[1], DST[2], DST[3], cntoff, pairs);
  bucket_final<<<NBUCK, 256, 0, stream>>>(cntoff, pairs, S, srcs);

  dim3 ggrid2((NNODE + 63) / 64);   // 782 blocks, full-N per block
  int nagg = NNODE / 4;             // 12500 blocks x 4 waves
  // ---- layer 1, dt=chemical: et1 (src gene) + et2 (src chem)
  agg_pair<<<nagg, 256, 0, stream>>>(S, srcs, xb_gene, 1, aggA, xb_chem, 2, aggB);
  gemm512<0><<<ggrid2, 256, 0, stream>>>(aggA, aggB, WTc1, B1[1], B1[2], S, 1, 2, h1_chem, NNODE);
  // ---- layer 1, dt=gene: et0 (src chem) + et3 (src gene)
  agg_pair<<<nagg, 256, 0, stream>>>(S, srcs, xb_chem, 0, aggA, xb_gene, 3, aggB);
  gemm512<0><<<ggrid2, 256, 0, stream>>>(aggA, aggB, WTg1, B1[0], B1[3], S, 0, 3, h1_gene, NNODE);
  // ---- layer 2, dt=chemical only: et1 (src h1_gene) + et2 (src h1_chem)
  agg_pair<<<nagg, 256, 0, stream>>>(S, srcs, h1_gene, 1, aggA, h1_chem, 2, aggB);
  gemm512<1><<<ggrid2, 256, 0, stream>>>(aggA, aggB, WTc2, B2[1], B2[2], S, 1, 2, d_out, NNODE);
}